// Round 12
// baseline (12051.372 us; speedup 1.0000x reference)
//
#include <hip/hip_runtime.h>
#include <stdint.h>

#define N_STEPS 2000
#define DT_F 0.01f

typedef float f32x2 __attribute__((ext_vector_type(2)));

// tanh(x) = 1 - 2/(exp2(2x*log2e)+1): mul, exp2, add, rcp, fma = 5 VALU.
__device__ __forceinline__ float fast_tanh(float x) {
    float e = __builtin_amdgcn_exp2f(x * 2.8853900817779268f);  // e^{2x}
    float r = __builtin_amdgcn_rcpf(e + 1.0f);
    return fmaf(-2.0f, r, 1.0f);
}

__device__ __forceinline__ float rl(float v, int lane) {
    return __builtin_bit_cast(float, __builtin_amdgcn_readlane(__builtin_bit_cast(int, v), lane));
}

template <int CTRL>
__device__ __forceinline__ float dpp_add(float v) {
    return v + __builtin_bit_cast(float, __builtin_amdgcn_update_dpp(
                   0, __builtin_bit_cast(int, v), CTRL, 0xf, 0xf, true));
}

// R5-style wave sum -> SGPR result. Pure-VALU DPP chain + one readlane:
// much lower serial latency than the bperm variants (2 DS round-trips).
__device__ __forceinline__ float wave_sum_s(float v) {
    v = dpp_add<0x111>(v);  // row_shr:1
    v = dpp_add<0x112>(v);  // row_shr:2
    v = dpp_add<0x114>(v);  // row_shr:4
    v = dpp_add<0x118>(v);  // row_shr:8  -> lanes 15/31/47/63 hold row sums
    v = dpp_add<0x142>(v);  // row_bcast15
    v = dpp_add<0x143>(v);  // row_bcast31 -> lane 63 = full sum
    return rl(v, 63);
}

// THE FIX vs R7-R11: the kernel has been L1-BW-bound re-streaming the W2
// column every eval (16 KB/sample-eval ~= 2.1 PB total ~= measured 13.4 ms).
// IR-level sinking defeats every "load once into registers" attempt UNLESS
// the loads are volatile (exactly-once semantics: cannot sink/remat). With
// amdgpu_waves_per_eu(2,2) the register target is ~256, so keeping the 64
// values live is free (R8's spill disaster came from the 64-reg target of
// launch_bounds(256,8)). Volatile LDS reads of a compiler-addressed buffer
// avoid R6's manual-LDS-address bug.
__global__ __attribute__((amdgpu_flat_work_group_size(256, 256),
                          amdgpu_waves_per_eu(2, 2)))
void node_rk4_kernel(
    const float* __restrict__ y0_in,
    const float* __restrict__ W1, const float* __restrict__ B1,
    const float* __restrict__ W2, const float* __restrict__ B2,
    const float* __restrict__ W3, const float* __restrict__ B3,
    float* __restrict__ out, int batch)
{
    __shared__ __align__(16) float sW2T[64 * 64];   // W2 transposed: [j][i]
    __shared__ __align__(16) float hl_all[4][64];

    const int tid  = threadIdx.x;
    const int lane = tid & 63;
    const int wib  = tid >> 6;                 // wave-in-block 0..3
    const int b    = blockIdx.x * 4 + wib;     // sample id

    // One-time stage of W2^T into LDS (coalesced global reads; the strided
    // LDS writes bank-conflict but it's 16 instructions, once).
    for (int idx = tid; idx < 64 * 64; idx += 256) {
        sW2T[(idx & 63) * 64 + (idx >> 6)] = W2[idx];
    }
    __syncthreads();

    if (b >= batch) return;

    const int j = lane;
    const float w1_0 = W1[j], w1_1 = W1[64 + j];
    const float b1v  = B1[j], b2v = B2[j];
    const float w3_0 = W3[2 * j], w3_1 = W3[2 * j + 1];
    // Fold b3 into lane 0's pre-reduction term.
    const float b3l0 = (lane == 0) ? B3[0] : 0.0f;
    const float b3l1 = (lane == 0) ? B3[1] : 0.0f;

    // Lane j's weight column -> 64 floats pinned in registers via VOLATILE
    // one-time LDS reads (exactly-once: LLVM must keep the values live).
    f32x2 w2p[32];
    {
        volatile const float* col = sW2T + (j << 6);
        #pragma unroll
        for (int i = 0; i < 32; ++i) {
            w2p[i].x = col[2 * i];
            w2p[i].y = col[2 * i + 1];
        }
    }

    float y0 = y0_in[2 * b + 0];
    float y1 = y0_in[2 * b + 1];

    float* outb = out + (size_t)b * (2 * (N_STEPS + 1));
    if (lane == 0) {
        reinterpret_cast<float2*>(outb)[0] = make_float2(y0, y1);
    }

    // Keep dt constants in VGPRs (k's are SGPRs after wave_sum_s; a VALU op
    // gets only one scalar operand, so these must be vector-resident).
    float chdt = 0.5f * DT_F, cdt = DT_F, cdt6 = DT_F / 6.0f;
    asm("" : "+v"(chdt), "+v"(cdt), "+v"(cdt6));

    float* hl = hl_all[wib];
    const f32x2* hp2 = (const f32x2*)hl;

    // net: wave-uniform (yi0,yi1) -> wave-uniform SGPR (o0,o1); lane j owns unit j.
    auto net = [&](float yi0, float yi1, float& o0, float& o1) {
        float pre = fmaf(yi0, w1_0, fmaf(yi1, w1_1, b1v));
        float h1  = fast_tanh(pre);
        hl[lane] = h1;
        __builtin_amdgcn_wave_barrier();   // write -> read ordering (in-wave DS order)

        f32x2 acc0 = (f32x2){b2v, 0.0f};
        f32x2 acc1 = (f32x2){0.0f, 0.0f};
        f32x2 acc2 = (f32x2){0.0f, 0.0f};
        f32x2 acc3 = (f32x2){0.0f, 0.0f};
        #pragma unroll
        for (int i = 0; i < 32; i += 4) {
            acc0 = __builtin_elementwise_fma(hp2[i + 0], w2p[i + 0], acc0);
            acc1 = __builtin_elementwise_fma(hp2[i + 1], w2p[i + 1], acc1);
            acc2 = __builtin_elementwise_fma(hp2[i + 2], w2p[i + 2], acc2);
            acc3 = __builtin_elementwise_fma(hp2[i + 3], w2p[i + 3], acc3);
        }
        __builtin_amdgcn_wave_barrier();   // reads done before next eval's write

        f32x2 s = (acc0 + acc1) + (acc2 + acc3);
        float h2 = fast_tanh(s.x + s.y);
        float p0 = fmaf(h2, w3_0, b3l0);
        float p1 = fmaf(h2, w3_1, b3l1);
        o0 = wave_sum_s(p0);
        o1 = wave_sum_s(p1);
    };

    for (int t = 1; t <= N_STEPS; ++t) {
        float k10, k11, k20, k21, k30, k31, k40, k41;
        net(y0, y1, k10, k11);
        net(fmaf(chdt, k10, y0), fmaf(chdt, k11, y1), k20, k21);
        net(fmaf(chdt, k20, y0), fmaf(chdt, k21, y1), k30, k31);
        net(fmaf(cdt,  k30, y0), fmaf(cdt,  k31, y1), k40, k41);
        float s0 = (k10 + k40) + 2.0f * (k20 + k30);
        float s1 = (k11 + k41) + 2.0f * (k21 + k31);
        y0 = fmaf(cdt6, s0, y0);
        y1 = fmaf(cdt6, s1, y1);
        if (lane == 0) {
            reinterpret_cast<float2*>(outb)[t] = make_float2(y0, y1);
        }
    }
}

extern "C" void kernel_launch(void* const* d_in, const int* in_sizes, int n_in,
                              void* d_out, int out_size, void* d_ws, size_t ws_size,
                              hipStream_t stream) {
    const float* y0 = (const float*)d_in[0];
    const float* W1 = (const float*)d_in[1];
    const float* B1 = (const float*)d_in[2];
    const float* W2 = (const float*)d_in[3];
    const float* B2 = (const float*)d_in[4];
    const float* W3 = (const float*)d_in[5];
    const float* B3 = (const float*)d_in[6];
    float* out = (float*)d_out;

    const int batch = in_sizes[0] / 2;
    const int blocks = (batch + 3) / 4;   // 4 waves (samples) per 256-thread block

    node_rk4_kernel<<<blocks, 256, 0, stream>>>(y0, W1, B1, W2, B2, W3, B3, out, batch);
}